// Round 15
// baseline (603.484 us; speedup 1.0000x reference)
//
#include <hip/hip_runtime.h>

typedef unsigned short u16;
typedef __attribute__((ext_vector_type(8))) short bf16x8;   // 8 bf16 (bit pattern), 4 VGPRs
typedef __attribute__((ext_vector_type(4))) float f32x4;

#define DEV __device__ __forceinline__
#define EXP2(x) __builtin_amdgcn_exp2f(x)
#define LOG2(x) __builtin_amdgcn_logf(x)

DEV u16 f2bf(float f) {
  union { float f; unsigned u; } v; v.f = f;
  unsigned r = v.u + 0x7fffu + ((v.u >> 16) & 1u);
  return (u16)(r >> 16);
}
DEV float bf2f(u16 h) {
  union { unsigned u; float f; } v; v.u = ((unsigned)h) << 16;
  return v.f;
}
DEV f32x4 mfma16(bf16x8 a, bf16x8 b, f32x4 c) {
  return __builtin_amdgcn_mfma_f32_16x16x32_bf16(a, b, c, 0, 0, 0);
}
DEV void cp16(const u16* g, u16* l) {
  __builtin_amdgcn_global_load_lds((__attribute__((address_space(1))) void*)g,
                                   (__attribute__((address_space(3))) void*)l, 16, 0, 0);
}

// ---------------- split x (fp32 -> bf16 hi + lo) ----------------
__global__ __launch_bounds__(256) void split_pair(const float4* __restrict__ x,
                                                  u16* __restrict__ hi, u16* __restrict__ lo) {
  const size_t i = (size_t)blockIdx.x * 256 + threadIdx.x;
  const float4 v = x[i];
  ushort4 h, l;
  h.x = f2bf(v.x); l.x = f2bf(v.x - bf2f(h.x));
  h.y = f2bf(v.y); l.y = f2bf(v.y - bf2f(h.y));
  h.z = f2bf(v.z); l.z = f2bf(v.z - bf2f(h.z));
  h.w = f2bf(v.w); l.w = f2bf(v.w - bf2f(h.w));
  *(ushort4*)&hi[i * 4] = h;
  *(ushort4*)&lo[i * 4] = l;
}

// ------------- transpose + split W: merged 3-way (z=0 Wq full, z=1 Wk full, z=2 Wv hi) -------------
__global__ __launch_bounds__(256) void transpose_all(
    const float* __restrict__ Wq, const float* __restrict__ Wk, const float* __restrict__ Wv,
    u16* __restrict__ qTh, u16* __restrict__ qTl,
    u16* __restrict__ kTh, u16* __restrict__ kTl, u16* __restrict__ vTh) {
  const float* W; u16* Th; u16* Tl; bool LO;
  if (blockIdx.z == 0)      { W = Wq; Th = qTh; Tl = qTl;     LO = true;  }
  else if (blockIdx.z == 1) { W = Wk; Th = kTh; Tl = kTl;     LO = true;  }
  else                      { W = Wv; Th = vTh; Tl = nullptr; LO = false; }
  __shared__ float t[64][65];
  const int r0 = blockIdx.y * 64, c0 = blockIdx.x * 64;
  const int rr = threadIdx.x >> 4, c4 = (threadIdx.x & 15) * 4;
#pragma unroll
  for (int p = 0; p < 4; ++p) {
    const float4 v = *(const float4*)&W[(size_t)(r0 + p * 16 + rr) * 2048 + c0 + c4];
    t[p * 16 + rr][c4 + 0] = v.x; t[p * 16 + rr][c4 + 1] = v.y;
    t[p * 16 + rr][c4 + 2] = v.z; t[p * 16 + rr][c4 + 3] = v.w;
  }
  __syncthreads();
#pragma unroll
  for (int p = 0; p < 4; ++p) {
    const int cc = p * 16 + rr;
    const float v0 = t[c4 + 0][cc], v1 = t[c4 + 1][cc], v2 = t[c4 + 2][cc], v3 = t[c4 + 3][cc];
    ushort4 h;
    h.x = f2bf(v0); h.y = f2bf(v1); h.z = f2bf(v2); h.w = f2bf(v3);
    *(ushort4*)&Th[(size_t)(c0 + cc) * 2048 + r0 + c4] = h;
    if (LO) {
      ushort4 l;
      l.x = f2bf(v0 - bf2f(h.x)); l.y = f2bf(v1 - bf2f(h.y));
      l.z = f2bf(v2 - bf2f(h.z)); l.w = f2bf(v3 - bf2f(h.w));
      *(ushort4*)&Tl[(size_t)(c0 + cc) * 2048 + r0 + c4] = l;
    }
  }
}

// ------------- transpose + split W (single, for Wo) -------------
template<bool LO>
__global__ __launch_bounds__(256) void transpose_split(const float* __restrict__ W,
                                                       u16* __restrict__ Th, u16* __restrict__ Tl) {
  __shared__ float t[64][65];
  const int r0 = blockIdx.y * 64, c0 = blockIdx.x * 64;
  const int rr = threadIdx.x >> 4, c4 = (threadIdx.x & 15) * 4;
#pragma unroll
  for (int p = 0; p < 4; ++p) {
    const float4 v = *(const float4*)&W[(size_t)(r0 + p * 16 + rr) * 2048 + c0 + c4];
    t[p * 16 + rr][c4 + 0] = v.x; t[p * 16 + rr][c4 + 1] = v.y;
    t[p * 16 + rr][c4 + 2] = v.z; t[p * 16 + rr][c4 + 3] = v.w;
  }
  __syncthreads();
#pragma unroll
  for (int p = 0; p < 4; ++p) {
    const int cc = p * 16 + rr;
    const float v0 = t[c4 + 0][cc], v1 = t[c4 + 1][cc], v2 = t[c4 + 2][cc], v3 = t[c4 + 3][cc];
    ushort4 h;
    h.x = f2bf(v0); h.y = f2bf(v1); h.z = f2bf(v2); h.w = f2bf(v3);
    *(ushort4*)&Th[(size_t)(c0 + cc) * 2048 + r0 + c4] = h;
    if constexpr (LO) {
      ushort4 l;
      l.x = f2bf(v0 - bf2f(h.x)); l.y = f2bf(v1 - bf2f(h.y));
      l.z = f2bf(v2 - bf2f(h.z)); l.w = f2bf(v3 - bf2f(h.w));
      *(ushort4*)&Tl[(size_t)(c0 + cc) * 2048 + r0 + c4] = l;
    }
  }
}

// ======== gemm_qkv2: block-interleaved merge of the R11-verified gemm_qk body (even
// blocks) and the R11-verified V-projection gemm_bt body (odd blocks). 1024 blocks,
// 48KB dynamic LDS, 3 blocks/CU (was 2 serial launches at 2/CU each). No inner-loop
// changes — each block executes one verbatim verified body.
__global__ __launch_bounds__(256, 2) void gemm_qkv2(
    const u16* __restrict__ Aph, const u16* __restrict__ Apl,
    const u16* __restrict__ Bqh, const u16* __restrict__ Bql,
    const u16* __restrict__ Bkh, const u16* __restrict__ Bkl,
    const u16* __restrict__ Bvh,
    u16* __restrict__ Qh, u16* __restrict__ Ql,
    u16* __restrict__ Kh, u16* __restrict__ Kl, u16* __restrict__ Vt) {
  extern __shared__ u16 lds[];
  char* ldsb = (char*)lds;
  const int tid = threadIdx.x;
  const int wave = tid >> 6, lane = tid & 63;
  const int li = lane & 15, l4 = lane >> 4;
  const int lin = ((int)blockIdx.y << 5) | (int)blockIdx.x;   // [0,1024), role-interleaved
  const int lin0 = lin >> 1;                                   // [0,512)
  const int xcd = lin0 & 7, idx = lin0 >> 3;
  const int m0 = ((xcd << 2) | (idx & 3)) * 128;
  const int n0 = (idx >> 2) * 128;
  const int wr = (wave >> 1) * 64, wc = (wave & 1) * 64;
  const f32x4 fz = {0.f, 0.f, 0.f, 0.f};

  if (lin & 1) {
    // ---------------- V body (m97-style, linear LDS; verbatim gemm_bt<2,false>) ----------------
    f32x4 acc[4][4];
#pragma unroll
    for (int m = 0; m < 4; ++m)
#pragma unroll
      for (int n = 0; n < 4; ++n) acc[m][n] = fz;

    const size_t aoff = (size_t)(m0 + (tid >> 2)) * 2048 + (tid & 3) * 8;
    const size_t boff = (size_t)(n0 + (tid >> 2)) * 2048 + (tid & 3) * 8;
    const size_t rstep = (size_t)64 * 2048;
    const int s0 = tid * 8, s1 = 2048 + tid * 8;
    const int abase = (wr + li) * 32 + l4 * 8;
    const int bbase = (wc + li) * 32 + l4 * 8;

#pragma unroll 1
    for (int k0 = 0; k0 < 2048; k0 += 32) {
      cp16(Aph + aoff + k0,         &lds[s0]);
      cp16(Aph + aoff + rstep + k0, &lds[s1]);
      cp16(Bvh + boff + k0,         &lds[4096 + s0]);
      cp16(Bvh + boff + rstep + k0, &lds[4096 + s1]);
      __syncthreads();
      bf16x8 af[4], bf_[4];
#pragma unroll
      for (int m = 0; m < 4; ++m) af[m] = *(const bf16x8*)&lds[abase + m * 512];
#pragma unroll
      for (int n = 0; n < 4; ++n) bf_[n] = *(const bf16x8*)&lds[4096 + bbase + n * 512];
#pragma unroll
      for (int m = 0; m < 4; ++m)
#pragma unroll
        for (int n = 0; n < 4; ++n)
          acc[m][n] = mfma16(af[m], bf_[n], acc[m][n]);
      __syncthreads();
    }

#pragma unroll
    for (int m = 0; m < 4; ++m) {
#pragma unroll
      for (int n = 0; n < 4; ++n) {
        const int rg0 = m0 + wr + m * 16 + l4 * 4;
        const int cg  = n0 + wc + n * 16 + li;
        ushort4 pk;
        pk.x = f2bf(acc[m][n][0]); pk.y = f2bf(acc[m][n][1]);
        pk.z = f2bf(acc[m][n][2]); pk.w = f2bf(acc[m][n][3]);
        *(ushort4*)&Vt[(size_t)(rg0 >> 11) * 4194304 + (size_t)cg * 2048 + (rg0 & 2047)] = pk;
      }
    }
  } else {
    // ---------------- QK body (verbatim R11-verified gemm_qk) ----------------
    f32x4 accQ[4][4], accK[4][4];
#pragma unroll
    for (int m = 0; m < 4; ++m)
#pragma unroll
      for (int n = 0; n < 4; ++n) { accQ[m][n] = fz; accK[m][n] = fz; }

    const int o = tid * 16;
    const int op = o ^ (((o >> 7) & 7) << 4);
    const int srow = op >> 6, scol = (op & 63) >> 1;
    const size_t aoff = (size_t)(m0 + srow) * 2048 + scol;
    const size_t boff = (size_t)(n0 + srow) * 2048 + scol;
    const size_t rstep = (size_t)64 * 2048;
    const int s0 = tid * 8, s1 = 2048 + tid * 8;

    const int arow = wr + li, brow = wc + li;
    const int rsA = (arow * 64 + l4 * 16) ^ (((arow >> 1) & 7) << 4);
    const int rsB = (brow * 64 + l4 * 16) ^ (((brow >> 1) & 7) << 4);

#pragma unroll 1
    for (int k0 = 0; k0 < 2048; k0 += 32) {
      cp16(Aph + aoff + k0,         &lds[s0]);
      cp16(Aph + aoff + rstep + k0, &lds[s1]);
      cp16(Apl + aoff + k0,         &lds[4096 + s0]);
      cp16(Apl + aoff + rstep + k0, &lds[4096 + s1]);
      cp16(Bqh + boff + k0,         &lds[8192 + s0]);
      cp16(Bqh + boff + rstep + k0, &lds[8192 + s1]);
      cp16(Bql + boff + k0,         &lds[12288 + s0]);
      cp16(Bql + boff + rstep + k0, &lds[12288 + s1]);
      cp16(Bkh + boff + k0,         &lds[16384 + s0]);
      cp16(Bkh + boff + rstep + k0, &lds[16384 + s1]);
      cp16(Bkl + boff + k0,         &lds[20480 + s0]);
      cp16(Bkl + boff + rstep + k0, &lds[20480 + s1]);
      __syncthreads();
      bf16x8 af[4], alf[4];
#pragma unroll
      for (int m = 0; m < 4; ++m) {
        af[m]  = *(const bf16x8*)(ldsb + rsA + m * 1024);
        alf[m] = *(const bf16x8*)(ldsb + 8192 + rsA + m * 1024);
      }
      {
        bf16x8 bh[4], bl[4];
#pragma unroll
        for (int n = 0; n < 4; ++n) {
          bh[n] = *(const bf16x8*)(ldsb + 16384 + rsB + n * 1024);
          bl[n] = *(const bf16x8*)(ldsb + 24576 + rsB + n * 1024);
        }
#pragma unroll
        for (int m = 0; m < 4; ++m)
#pragma unroll
          for (int n = 0; n < 4; ++n) {
            accQ[m][n] = mfma16(af[m], bh[n], accQ[m][n]);
            accQ[m][n] = mfma16(af[m], bl[n], accQ[m][n]);
            accQ[m][n] = mfma16(alf[m], bh[n], accQ[m][n]);
          }
      }
      {
        bf16x8 bh[4], bl[4];
#pragma unroll
        for (int n = 0; n < 4; ++n) {
          bh[n] = *(const bf16x8*)(ldsb + 32768 + rsB + n * 1024);
          bl[n] = *(const bf16x8*)(ldsb + 40960 + rsB + n * 1024);
        }
#pragma unroll
        for (int m = 0; m < 4; ++m)
#pragma unroll
          for (int n = 0; n < 4; ++n) {
            accK[m][n] = mfma16(af[m], bh[n], accK[m][n]);
            accK[m][n] = mfma16(af[m], bl[n], accK[m][n]);
            accK[m][n] = mfma16(alf[m], bh[n], accK[m][n]);
          }
      }
      __syncthreads();
    }

#pragma unroll
    for (int m = 0; m < 4; ++m) {
#pragma unroll
      for (int n = 0; n < 4; ++n) {
        const int rg0 = m0 + wr + m * 16 + l4 * 4;
        const int cg  = n0 + wc + n * 16 + li;
#pragma unroll
        for (int r = 0; r < 4; ++r) {
          const float vq = accQ[m][n][r];
          const u16 hq = f2bf(vq);
          Qh[(size_t)(rg0 + r) * 2048 + cg] = hq;
          Ql[(size_t)(rg0 + r) * 2048 + cg] = f2bf(vq - bf2f(hq));
          const float vk = accK[m][n][r];
          const u16 hk = f2bf(vk);
          Kh[(size_t)(rg0 + r) * 2048 + cg] = hk;
          Kl[(size_t)(rg0 + r) * 2048 + cg] = f2bf(vk - bf2f(hk));
        }
      }
    }
  }
}

// ---------------- GEMM: C[M,N] = A[M,K] @ Bt[N,K]^T  (m97-style 128x128 tile) ----------------
template<int OUTMODE, bool KLIM>
__global__ __launch_bounds__(256, 2) void gemm_bt(
    const u16* __restrict__ Aph, const u16* __restrict__ Bph,
    void* __restrict__ C0,
    const int M, const int N, const int K, const int bShift) {
  extern __shared__ u16 lds[];
  constexpr int T_BH = 4096;
  const int tid = threadIdx.x;
  const int wave = tid >> 6, lane = tid & 63;
  const int li = lane & 15, l4 = lane >> 4;
  const int lin0 = ((int)blockIdx.y << 4) | (int)blockIdx.x;
  const int xcd = lin0 & 7, idx = lin0 >> 3;
  const int m0 = ((xcd << 2) | (idx & 3)) * 128;
  const int n0 = (idx >> 2) * 128;
  const int wr = (wave >> 1) * 64, wc = (wave & 1) * 64;
  const u16* Bh = Bph;
  if (bShift) { const size_t s = (size_t)(m0 >> 11) * (size_t)bShift; Bh += s; }

  const f32x4 fz = {0.f, 0.f, 0.f, 0.f};
  f32x4 acc[4][4];
#pragma unroll
  for (int m = 0; m < 4; ++m)
#pragma unroll
    for (int n = 0; n < 4; ++n) acc[m][n] = fz;

  const size_t aoff = (size_t)(m0 + (tid >> 2)) * K + (tid & 3) * 8;
  const size_t boff = (size_t)(n0 + (tid >> 2)) * K + (tid & 3) * 8;
  const size_t rstep = (size_t)64 * K;
  const int s0 = tid * 8, s1 = 2048 + tid * 8;
  const int abase = (wr + li) * 32 + l4 * 8;
  const int bbase = (wc + li) * 32 + l4 * 8;
  const int kEnd = KLIM ? ((m0 & 2047) + 128 < K ? (m0 & 2047) + 128 : K) : K;

#pragma unroll 1
  for (int k0 = 0; k0 < kEnd; k0 += 32) {
    cp16(Aph + aoff + k0,         &lds[s0]);
    cp16(Aph + aoff + rstep + k0, &lds[s1]);
    cp16(Bh + boff + k0,          &lds[T_BH + s0]);
    cp16(Bh + boff + rstep + k0,  &lds[T_BH + s1]);
    __syncthreads();
    bf16x8 af[4], bf_[4];
#pragma unroll
    for (int m = 0; m < 4; ++m) af[m] = *(const bf16x8*)&lds[abase + m * 512];
#pragma unroll
    for (int n = 0; n < 4; ++n) bf_[n] = *(const bf16x8*)&lds[T_BH + bbase + n * 512];
#pragma unroll
    for (int m = 0; m < 4; ++m)
#pragma unroll
      for (int n = 0; n < 4; ++n)
        acc[m][n] = mfma16(af[m], bf_[n], acc[m][n]);
    __syncthreads();
  }

#pragma unroll
  for (int m = 0; m < 4; ++m) {
#pragma unroll
    for (int n = 0; n < 4; ++n) {
      const int rg0 = m0 + wr + m * 16 + l4 * 4;
      const int cg  = n0 + wc + n * 16 + li;
      if constexpr (OUTMODE == 1) {
        u16* Cs = (u16*)C0;
#pragma unroll
        for (int r = 0; r < 4; ++r) Cs[(size_t)(rg0 + r) * N + cg] = f2bf(acc[m][n][r]);
      } else {
        float* Cf = (float*)C0;
#pragma unroll
        for (int r = 0; r < 4; ++r) Cf[(size_t)(rg0 + r) * N + cg] = acc[m][n][r];
      }
    }
  }
}

// ================= two-pass causal attention, swizzled LDS-staged K =================
#define C2EXP 0.1275174381027786f   // SCALE * log2(e)

// ---- pass A (split-k): partial (m,l) per 512-wide k chunk (R11-verified) ----
__global__ __launch_bounds__(256) void attn_lse_part(
    const u16* __restrict__ Qh, const u16* __restrict__ Ql,
    const u16* __restrict__ Kh, const u16* __restrict__ Kl,
    float* __restrict__ Mp, float* __restrict__ Lp) {
  const int j = blockIdx.x, qt = 15 - (int)blockIdx.y, hb = blockIdx.z;
  const int b = hb >> 4, h = hb & 15;
  const int tid = threadIdx.x;
  const int nch = (qt >> 2) + 1;
  if (j >= nch) {
    if (tid < 128) {
      const size_t o = ((size_t)hb * 4 + j) * 2048 + qt * 128 + tid;
      Mp[o] = -3.0e38f; Lp[o] = 0.f;
    }
    return;
  }
  __shared__ __align__(16) u16 kb[16384];
  const int wave = tid >> 6, lane = tid & 63;
  const int li = lane & 15, l4 = lane >> 4;
  const int q0w = qt * 128 + wave * 32;
  const int rs = ((li << 6) | (l4 << 4)) ^ (((li >> 1) & 7) << 4);

  bf16x8 qfh[2][4], qfl[2][4];
#pragma unroll
  for (int mf = 0; mf < 2; ++mf) {
    const size_t qo = ((size_t)(b * 2048 + q0w + mf * 16 + li)) * 2048 + h * 128 + l4 * 8;
#pragma unroll
    for (int ks = 0; ks < 4; ++ks) {
      qfh[mf][ks] = *(const bf16x8*)&Qh[qo + ks * 32];
      qfl[mf][ks] = *(const bf16x8*)&Ql[qo + ks * 32];
    }
  }
  float m[2][4], l[2][4];
#pragma unroll
  for (int mf = 0; mf < 2; ++mf)
#pragma unroll
    for (int r = 0; r < 4; ++r) { m[mf][r] = -3.0e38f; l[mf][r] = 0.f; }

  const int kst = j * 8;
  const int ken = min(j * 8 + 8, qt * 2 + 2);
  const size_t kgbase = ((size_t)b * 2048) * 2048 + h * 128;
  const f32x4 fz = {0.f, 0.f, 0.f, 0.f};

#pragma unroll 1
  for (int t = kst; t < ken; ++t) {
    __syncthreads();
#pragma unroll
    for (int i = 0; i < 4; ++i) {
      const int o = (tid + i * 256) * 16;
      const int op = o ^ (((o >> 7) & 7) << 4);
      const int dck = op >> 12, s = (op >> 6) & 63, dl = (op >> 1) & 31;
      const size_t g = kgbase + (size_t)(t * 64 + s) * 2048 + dck * 32 + dl;
      cp16(Kh + g, kb + (o >> 1));
      cp16(Kl + g, kb + 8192 + (o >> 1));
    }
    __syncthreads();
#pragma unroll
    for (int sn = 0; sn < 4; ++sn) {
      if (64 * t + 16 * sn <= q0w + 31) {
        f32x4 a0 = fz, a1 = fz;
        __builtin_amdgcn_s_setprio(1);
#pragma unroll
        for (int ks = 0; ks < 4; ++ks) {
          const bf16x8 kh = *(const bf16x8*)((const char*)kb + ks * 4096 + (sn << 10) + rs);
          const bf16x8 kl = *(const bf16x8*)((const char*)kb + 16384 + ks * 4096 + (sn << 10) + rs);
          a0 = mfma16(qfh[0][ks], kh, a0);
          a0 = mfma16(qfh[0][ks], kl, a0);
          a0 = mfma16(qfl[0][ks], kh, a0);
          a1 = mfma16(qfh[1][ks], kh, a1);
          a1 = mfma16(qfh[1][ks], kl, a1);
          a1 = mfma16(qfl[1][ks], kh, a1);
        }
        __builtin_amdgcn_s_setprio(0);
        const int kg = t * 64 + sn * 16 + li;
#pragma unroll
        for (int r = 0; r < 4; ++r) {
          {
            const float aa = (kg <= q0w + l4 * 4 + r) ? a0[r] : -3.3e38f;
            if (__all(aa <= m[0][r])) {
              l[0][r] += EXP2((aa - m[0][r]) * C2EXP);
            } else {
              const float mn = fmaxf(m[0][r], aa);
              l[0][r] = l[0][r] * EXP2((m[0][r] - mn) * C2EXP) + EXP2((aa - mn) * C2EXP);
              m[0][r] = mn;
            }
          }
          {
            const float aa = (kg <= q0w + 16 + l4 * 4 + r) ? a1[r] : -3.3e38f;
            if (__all(aa <= m[1][r])) {
              l[1][r] += EXP2((aa - m[1][r]) * C2EXP);
            } else {
              const float mn = fmaxf(m[1][r], aa);
              l[1][r] = l[1][r] * EXP2((m[1][r] - mn) * C2EXP) + EXP2((aa - mn) * C2EXP);
              m[1][r] = mn;
            }
          }
        }
      }
    }
  }
#pragma unroll
  for (int off = 1; off <= 8; off <<= 1) {
#pragma unroll
    for (int mf = 0; mf < 2; ++mf)
#pragma unroll
      for (int r = 0; r < 4; ++r) {
        const float om = __shfl_xor(m[mf][r], off, 64);
        const float ol = __shfl_xor(l[mf][r], off, 64);
        const float mn = fmaxf(m[mf][r], om);
        l[mf][r] = l[mf][r] * EXP2((m[mf][r] - mn) * C2EXP) + ol * EXP2((om - mn) * C2EXP);
        m[mf][r] = mn;
      }
  }
  if (li == 0) {
#pragma unroll
    for (int mf = 0; mf < 2; ++mf)
#pragma unroll
      for (int r = 0; r < 4; ++r) {
        const size_t o = ((size_t)hb * 4 + j) * 2048 + q0w + mf * 16 + l4 * 4 + r;
        Mp[o] = m[mf][r];
        Lp[o] = l[mf][r];
      }
  }
}

// ---- pass A merge ----
__global__ __launch_bounds__(256) void attn_lse_merge(
    const float* __restrict__ Mp, const float* __restrict__ Lp, float* __restrict__ LSE) {
  const int id = blockIdx.x * 256 + threadIdx.x;
  const int q = id & 2047, hb = id >> 11;
  const size_t base = (size_t)hb * 4 * 2048 + q;
  float m = Mp[base], l = Lp[base];
#pragma unroll
  for (int jj = 1; jj < 4; ++jj) {
    const float om = Mp[base + jj * 2048];
    const float ol = Lp[base + jj * 2048];
    const float mn = fmaxf(m, om);
    l = l * EXP2((m - mn) * C2EXP) + ol * EXP2((om - mn) * C2EXP);
    m = mn;
  }
  LSE[(size_t)hb * 2048 + q] = m * C2EXP + LOG2(l);
}

// ---- pass B: Psum (R11-verified: 128q x 128k tiles, 64KB dyn LDS) ----
__global__ __launch_bounds__(256) void attn_psum(
    const u16* __restrict__ Qh, const u16* __restrict__ Ql,
    const u16* __restrict__ Kh, const u16* __restrict__ Kl,
    const float* __restrict__ LSE, u16* __restrict__ Psum) {
  const int kt = blockIdx.x, qt = blockIdx.y, b = blockIdx.z;
  const int q0 = qt * 128, k0 = kt * 128;
  const int tid = threadIdx.x;

  if (kt > qt) {
    const size_t o = ((size_t)(b * 2048 + q0 + (tid >> 1))) * 2048 + k0 + (tid & 1) * 64;
    const uint4 z = {0u, 0u, 0u, 0u};
#pragma unroll
    for (int j2 = 0; j2 < 8; ++j2) *(uint4*)&Psum[o + j2 * 8] = z;
    return;
  }

  extern __shared__ u16 kb2[];   // 65536 B
  const int wave = tid >> 6, lane = tid & 63;
  const int li = lane & 15, l4 = lane >> 4;
  const int q0w = q0 + wave * 32;
  const int rs = ((li << 6) | (l4 << 4)) ^ (((li >> 1) & 7) << 4);
  const int snmax = (kt == qt) ? (wave * 2 + 2) : 8;

  const f32x4 fz = {0.f, 0.f, 0.f, 0.f};
  f32x4 ps[2][8];
#pragma unroll
  for (int mf = 0; mf < 2; ++mf)
#pragma unroll
    for (int sn = 0; sn < 8; ++sn) ps[mf][sn] = fz;

  const size_t kgbase = ((size_t)(b * 2048 + k0)) * 2048;
  const size_t qbase0 = ((size_t)(b * 2048 + q0w + li)) * 2048 + l4 * 8;
  const size_t qbase1 = qbase0 + (size_t)16 * 2048;
  const size_t lbase  = (size_t)(b * 16) * 2048 + q0w + l4 * 4;

#pragma unroll 1
  for (int h = 0; h < 16; ++h) {
    __syncthreads();
#pragma unroll
    for (int i = 0; i < 8; ++i) {
      const int o = (tid + i * 256) * 16;
      const int op = o ^ (((o >> 7) & 7) << 4);
      const int dck = op >> 13, s = (op >> 6) & 127, dl = (op >> 1) & 31;
      const size_t g = kgbase + (size_t)s * 2048 + h * 128 + dck * 32 + dl;
      cp16(Kh + g, kb2 + (o >> 1));
      cp16(Kl + g, kb2 + 16384 + (o >> 1));
    }
    bf16x8 qfh0[4], qfl0[4], qfh1[4], qfl1[4];
    float clse[2][4];
#pragma unroll
    for (int ks = 0; ks < 4; ++ks) {
      qfh0[ks] = *(const bf16x8*)&Qh[qbase0 + (size_t)h * 128 + ks * 32];
      qfl0[ks] = *(const bf16x8*)&Ql[qbase0 + (size_t)h * 128 + ks * 32];
      qfh1[ks] = *(const bf16x8*)&Qh[qbase1 + (size_t)h * 128 + ks * 32];
      qfl1[ks] = *(const bf16x8*)&Ql[qbase1 + (size_t)h * 128 + ks * 32];
    }
#pragma unroll
    for (int mf = 0; mf < 2; ++mf)
#pragma unroll
      for (int r = 0; r < 4; ++r)
        clse[mf][r] = LSE[lbase + (size_t)h * 2048 + mf * 16 + r];
    __syncthreads();

#pragma unroll
    for (int sn = 0; sn < 8; ++sn) {
      if (sn < snmax) {
        f32x4 a0 = fz, a1 = fz;
        __builtin_amdgcn_s_setprio(1);
#pragma unroll
        for (int ks = 0; ks < 4; ++ks) {
          const bf16x8 kh = *(const bf16x8*)((const char*)kb2 + ks * 8192 + (sn << 10) + rs);
          const bf16x8 kl = *(const bf16x8*)((const char*)kb2 + 32768 + ks * 8192 + (sn << 10) + rs);
          a0 = mfma16(qfh0[ks], kh, a0);
          a0 = mfma16(qfh0[ks], kl, a0);
          a0 = mfma16(qfl0[ks], kh, a0);
          a1 = mfma16(qfh1[ks], kh, a1);
          a1 = mfma16(qfh1[ks], kl, a1);
          a1 = mfma16(qfl1[ks], kh, a1);
        }
        __builtin_amdgcn_s_setprio(0);
        const int kg = k0 + sn * 16 + li;
#pragma unroll
        for (int r = 0; r < 4; ++r) {
          if (kg <= q0w + l4 * 4 + r)      ps[0][sn][r] += EXP2(a0[r] * C2EXP - clse[0][r]);
          if (kg <= q0w + 16 + l4 * 4 + r) ps[1][sn][r] += EXP2(a1[r] * C2EXP - clse[1][r]);
        }
      }
    }
  }

#pragma unroll
  for (int mf = 0; mf < 2; ++mf)
#pragma unroll
    for (int sn = 0; sn < 8; ++sn) {
      const size_t o0 = ((size_t)(b * 2048 + q0w + mf * 16 + l4 * 4)) * 2048 + k0 + sn * 16 + li;
#pragma unroll
      for (int r = 0; r < 4; ++r) Psum[o0 + (size_t)r * 2048] = f2bf(ps[mf][sn][r]);
    }
}

// ---------------- launch ----------------
extern "C" void kernel_launch(void* const* d_in, const int* in_sizes, int n_in,
                              void* d_out, int out_size, void* d_ws, size_t ws_size,
                              hipStream_t stream) {
  (void)in_sizes; (void)n_in; (void)out_size; (void)ws_size;
  const float* x  = (const float*)d_in[0];
  const float* Wq = (const float*)d_in[1];
  const float* Wk = (const float*)d_in[2];
  const float* Wv = (const float*)d_in[3];
  const float* Wo = (const float*)d_in[4];
  u16* ws = (u16*)d_ws;
  const size_t E8 = 8388608, E4 = 4194304;
  u16* xh = ws;
  u16* xl = ws + E8;
  u16* Qh = ws + 2 * E8;
  u16* Ql = ws + 3 * E8;
  u16* Kh = ws + 4 * E8;
  u16* Kl = ws + 5 * E8;
  u16* Vt = ws + 6 * E8;            // [b][d][s]
  u16* WTh = ws + 7 * E8;           // WqT hi
  u16* WTl = ws + 7 * E8 + E4;      // WqT lo (LSE/partials after Q/K done)
  u16* WTb = ws + 7 * E8 + 2 * E4;  // WvT hi, later WoT hi
  u16* WkTh = ws + 7 * E8 + 3 * E4; // dedicated WkT (ws >= 152 MiB confirmed R13)
  u16* WkTl = ws + 7 * E8 + 4 * E4;
  float* LSEf = (float*)WTl;        // 65536 f32
  float* Mp   = LSEf + 65536;       // 262144 f32
  float* Lp   = Mp + 262144;        // 262144 f32
  u16* Psum = xl;
  u16* out1 = xh;
  // total ws use: 7*E8 + 5*E4 = 152 MiB

  split_pair<<<8192, 256, 0, stream>>>((const float4*)x, xh, xl);

  transpose_all<<<dim3(32, 32, 3), 256, 0, stream>>>(
      Wq, Wk, Wv, WTh, WTl, WkTh, WkTl, WTb);

  // merged Q+K (shared-A, swizzled) + V projection: 1024 interleaved blocks, 48KB LDS
  gemm_qkv2<<<dim3(32, 32), 256, 49152, stream>>>(
      xh, xl, WTh, WTl, WkTh, WkTl, WTb, Qh, Ql, Kh, Kl, Vt);

  attn_lse_part<<<dim3(4, 16, 32), 256, 0, stream>>>(Qh, Ql, Kh, Kl, Mp, Lp);
  attn_lse_merge<<<256, 256, 0, stream>>>(Mp, Lp, LSEf);
  attn_psum<<<dim3(16, 16, 2), 256, 65536, stream>>>(Qh, Ql, Kh, Kl, LSEf, Psum);

  gemm_bt<1, true><<<dim3(16, 32), 256, 16384, stream>>>(
      Psum, Vt, out1, 4096, 2048, 2048, 4194304);

  transpose_split<false><<<dim3(32, 32), 256, 0, stream>>>(Wo, WTb, nullptr);
  gemm_bt<3, false><<<dim3(16, 32), 256, 16384, stream>>>(
      out1, WTb, d_out, 4096, 2048, 2048, 0);
}

// Round 16
// 565.111 us; speedup vs baseline: 1.0679x; 1.0679x over previous
//
#include <hip/hip_runtime.h>

typedef unsigned short u16;
typedef __attribute__((ext_vector_type(8))) short bf16x8;   // 8 bf16 (bit pattern), 4 VGPRs
typedef __attribute__((ext_vector_type(4))) float f32x4;

#define DEV __device__ __forceinline__
#define EXP2(x) __builtin_amdgcn_exp2f(x)
#define LOG2(x) __builtin_amdgcn_logf(x)

DEV u16 f2bf(float f) {
  union { float f; unsigned u; } v; v.f = f;
  unsigned r = v.u + 0x7fffu + ((v.u >> 16) & 1u);
  return (u16)(r >> 16);
}
DEV float bf2f(u16 h) {
  union { unsigned u; float f; } v; v.u = ((unsigned)h) << 16;
  return v.f;
}
DEV f32x4 mfma16(bf16x8 a, bf16x8 b, f32x4 c) {
  return __builtin_amdgcn_mfma_f32_16x16x32_bf16(a, b, c, 0, 0, 0);
}
DEV void cp16(const u16* g, u16* l) {
  __builtin_amdgcn_global_load_lds((__attribute__((address_space(1))) void*)g,
                                   (__attribute__((address_space(3))) void*)l, 16, 0, 0);
}

// ---------------- split x (fp32 -> bf16 hi + lo) ----------------
__global__ __launch_bounds__(256) void split_pair(const float4* __restrict__ x,
                                                  u16* __restrict__ hi, u16* __restrict__ lo) {
  const size_t i = (size_t)blockIdx.x * 256 + threadIdx.x;
  const float4 v = x[i];
  ushort4 h, l;
  h.x = f2bf(v.x); l.x = f2bf(v.x - bf2f(h.x));
  h.y = f2bf(v.y); l.y = f2bf(v.y - bf2f(h.y));
  h.z = f2bf(v.z); l.z = f2bf(v.z - bf2f(h.z));
  h.w = f2bf(v.w); l.w = f2bf(v.w - bf2f(h.w));
  *(ushort4*)&hi[i * 4] = h;
  *(ushort4*)&lo[i * 4] = l;
}

// ------------- transpose + split W (fp32 [K][N] -> bf16 [N][K] hi(,lo)) -------------
template<bool LO>
__global__ __launch_bounds__(256) void transpose_split(const float* __restrict__ W,
                                                       u16* __restrict__ Th, u16* __restrict__ Tl) {
  __shared__ float t[64][65];
  const int r0 = blockIdx.y * 64, c0 = blockIdx.x * 64;
  const int rr = threadIdx.x >> 4, c4 = (threadIdx.x & 15) * 4;
#pragma unroll
  for (int p = 0; p < 4; ++p) {
    const float4 v = *(const float4*)&W[(size_t)(r0 + p * 16 + rr) * 2048 + c0 + c4];
    t[p * 16 + rr][c4 + 0] = v.x; t[p * 16 + rr][c4 + 1] = v.y;
    t[p * 16 + rr][c4 + 2] = v.z; t[p * 16 + rr][c4 + 3] = v.w;
  }
  __syncthreads();
#pragma unroll
  for (int p = 0; p < 4; ++p) {
    const int cc = p * 16 + rr;
    const float v0 = t[c4 + 0][cc], v1 = t[c4 + 1][cc], v2 = t[c4 + 2][cc], v3 = t[c4 + 3][cc];
    ushort4 h;
    h.x = f2bf(v0); h.y = f2bf(v1); h.z = f2bf(v2); h.w = f2bf(v3);
    *(ushort4*)&Th[(size_t)(c0 + cc) * 2048 + r0 + c4] = h;
    if constexpr (LO) {
      ushort4 l;
      l.x = f2bf(v0 - bf2f(h.x)); l.y = f2bf(v1 - bf2f(h.y));
      l.z = f2bf(v2 - bf2f(h.z)); l.w = f2bf(v3 - bf2f(h.w));
      *(ushort4*)&Tl[(size_t)(c0 + cc) * 2048 + r0 + c4] = l;
    }
  }
}

// ======== gemm_qk: dual-B split-3 GEMM — Q = A@Bq^T, K = A@Bk^T sharing A staging ========
// 128x128 tiles, grid (16 n, 32 m) XCD-banded. LDS 48KB, six 8KB regions:
//   Ah 0 | Al 8192 | Bqh 16384 | Bql 24576 | Bkh 32768 | Bkl 40960  (byte offsets)
// Each region: [128 rows][64 B] with XOR swizzle byte ^= ((byte>>7)&7)<<4.
// Staging keeps linear dest and pre-permutes the SOURCE; reads fold the XOR into rsA/rsB.
// R11-verified: 168 µs, MfmaUtil 57%, bank conflicts 0.
__global__ __launch_bounds__(256, 2) void gemm_qk(
    const u16* __restrict__ Aph, const u16* __restrict__ Apl,
    const u16* __restrict__ Bqh, const u16* __restrict__ Bql,
    const u16* __restrict__ Bkh, const u16* __restrict__ Bkl,
    u16* __restrict__ Qh, u16* __restrict__ Ql,
    u16* __restrict__ Kh, u16* __restrict__ Kl) {
  extern __shared__ u16 lds[];
  char* ldsb = (char*)lds;
  const int tid = threadIdx.x;
  const int wave = tid >> 6, lane = tid & 63;
  const int li = lane & 15, l4 = lane >> 4;
  const int lin0 = ((int)blockIdx.y << 4) | (int)blockIdx.x;   // 512 blocks
  const int xcd = lin0 & 7, idx = lin0 >> 3;                   // idx in [0,64)
  const int m0 = ((xcd << 2) | (idx & 3)) * 128;               // [0,4096), banded per XCD
  const int n0 = (idx >> 2) * 128;                             // [0,2048)
  const int wr = (wave >> 1) * 64, wc = (wave & 1) * 64;

  const f32x4 fz = {0.f, 0.f, 0.f, 0.f};
  f32x4 accQ[4][4], accK[4][4];
#pragma unroll
  for (int m = 0; m < 4; ++m)
#pragma unroll
    for (int n = 0; n < 4; ++n) { accQ[m][n] = fz; accK[m][n] = fz; }

  const int o = tid * 16;
  const int op = o ^ (((o >> 7) & 7) << 4);
  const int srow = op >> 6, scol = (op & 63) >> 1;
  const size_t aoff = (size_t)(m0 + srow) * 2048 + scol;
  const size_t boff = (size_t)(n0 + srow) * 2048 + scol;
  const size_t rstep = (size_t)64 * 2048;
  const int s0 = tid * 8, s1 = 2048 + tid * 8;

  const int arow = wr + li, brow = wc + li;
  const int rsA = (arow * 64 + l4 * 16) ^ (((arow >> 1) & 7) << 4);
  const int rsB = (brow * 64 + l4 * 16) ^ (((brow >> 1) & 7) << 4);

#pragma unroll 1
  for (int k0 = 0; k0 < 2048; k0 += 32) {
    cp16(Aph + aoff + k0,         &lds[s0]);
    cp16(Aph + aoff + rstep + k0, &lds[s1]);
    cp16(Apl + aoff + k0,         &lds[4096 + s0]);
    cp16(Apl + aoff + rstep + k0, &lds[4096 + s1]);
    cp16(Bqh + boff + k0,         &lds[8192 + s0]);
    cp16(Bqh + boff + rstep + k0, &lds[8192 + s1]);
    cp16(Bql + boff + k0,         &lds[12288 + s0]);
    cp16(Bql + boff + rstep + k0, &lds[12288 + s1]);
    cp16(Bkh + boff + k0,         &lds[16384 + s0]);
    cp16(Bkh + boff + rstep + k0, &lds[16384 + s1]);
    cp16(Bkl + boff + k0,         &lds[20480 + s0]);
    cp16(Bkl + boff + rstep + k0, &lds[20480 + s1]);
    __syncthreads();
    bf16x8 af[4], alf[4];
#pragma unroll
    for (int m = 0; m < 4; ++m) {
      af[m]  = *(const bf16x8*)(ldsb + rsA + m * 1024);
      alf[m] = *(const bf16x8*)(ldsb + 8192 + rsA + m * 1024);
    }
    {
      bf16x8 bh[4], bl[4];
#pragma unroll
      for (int n = 0; n < 4; ++n) {
        bh[n] = *(const bf16x8*)(ldsb + 16384 + rsB + n * 1024);
        bl[n] = *(const bf16x8*)(ldsb + 24576 + rsB + n * 1024);
      }
#pragma unroll
      for (int m = 0; m < 4; ++m)
#pragma unroll
        for (int n = 0; n < 4; ++n) {
          accQ[m][n] = mfma16(af[m], bh[n], accQ[m][n]);
          accQ[m][n] = mfma16(af[m], bl[n], accQ[m][n]);
          accQ[m][n] = mfma16(alf[m], bh[n], accQ[m][n]);
        }
    }
    {
      bf16x8 bh[4], bl[4];
#pragma unroll
      for (int n = 0; n < 4; ++n) {
        bh[n] = *(const bf16x8*)(ldsb + 32768 + rsB + n * 1024);
        bl[n] = *(const bf16x8*)(ldsb + 40960 + rsB + n * 1024);
      }
#pragma unroll
      for (int m = 0; m < 4; ++m)
#pragma unroll
        for (int n = 0; n < 4; ++n) {
          accK[m][n] = mfma16(af[m], bh[n], accK[m][n]);
          accK[m][n] = mfma16(af[m], bl[n], accK[m][n]);
          accK[m][n] = mfma16(alf[m], bh[n], accK[m][n]);
        }
    }
    __syncthreads();
  }

#pragma unroll
  for (int m = 0; m < 4; ++m) {
#pragma unroll
    for (int n = 0; n < 4; ++n) {
      const int rg0 = m0 + wr + m * 16 + l4 * 4;
      const int cg  = n0 + wc + n * 16 + li;
#pragma unroll
      for (int r = 0; r < 4; ++r) {
        const float vq = accQ[m][n][r];
        const u16 hq = f2bf(vq);
        Qh[(size_t)(rg0 + r) * 2048 + cg] = hq;
        Ql[(size_t)(rg0 + r) * 2048 + cg] = f2bf(vq - bf2f(hq));
        const float vk = accK[m][n][r];
        const u16 hk = f2bf(vk);
        Kh[(size_t)(rg0 + r) * 2048 + cg] = hk;
        Kl[(size_t)(rg0 + r) * 2048 + cg] = f2bf(vk - bf2f(hk));
      }
    }
  }
}

// ---------------- GEMM: C[M,N] = A[M,K] @ Bt[N,K]^T  (m97-style 128x128 tile) ----------------
// Grid (16, 32), XCD-banded swizzle (bijective). KLIM: stop K loop at (m0&2047)+128.
template<int OUTMODE, bool KLIM>
__global__ __launch_bounds__(256, 2) void gemm_bt(
    const u16* __restrict__ Aph, const u16* __restrict__ Bph,
    void* __restrict__ C0,
    const int M, const int N, const int K, const int bShift) {
  extern __shared__ u16 lds[];
  constexpr int T_BH = 4096;
  const int tid = threadIdx.x;
  const int wave = tid >> 6, lane = tid & 63;
  const int li = lane & 15, l4 = lane >> 4;
  const int lin0 = ((int)blockIdx.y << 4) | (int)blockIdx.x;
  const int xcd = lin0 & 7, idx = lin0 >> 3;
  const int m0 = ((xcd << 2) | (idx & 3)) * 128;
  const int n0 = (idx >> 2) * 128;
  const int wr = (wave >> 1) * 64, wc = (wave & 1) * 64;
  const u16* Bh = Bph;
  if (bShift) { const size_t s = (size_t)(m0 >> 11) * (size_t)bShift; Bh += s; }

  const f32x4 fz = {0.f, 0.f, 0.f, 0.f};
  f32x4 acc[4][4];
#pragma unroll
  for (int m = 0; m < 4; ++m)
#pragma unroll
    for (int n = 0; n < 4; ++n) acc[m][n] = fz;

  const size_t aoff = (size_t)(m0 + (tid >> 2)) * K + (tid & 3) * 8;
  const size_t boff = (size_t)(n0 + (tid >> 2)) * K + (tid & 3) * 8;
  const size_t rstep = (size_t)64 * K;
  const int s0 = tid * 8, s1 = 2048 + tid * 8;
  const int abase = (wr + li) * 32 + l4 * 8;
  const int bbase = (wc + li) * 32 + l4 * 8;
  const int kEnd = KLIM ? ((m0 & 2047) + 128 < K ? (m0 & 2047) + 128 : K) : K;

#pragma unroll 1
  for (int k0 = 0; k0 < kEnd; k0 += 32) {
    cp16(Aph + aoff + k0,         &lds[s0]);
    cp16(Aph + aoff + rstep + k0, &lds[s1]);
    cp16(Bh + boff + k0,          &lds[T_BH + s0]);
    cp16(Bh + boff + rstep + k0,  &lds[T_BH + s1]);
    __syncthreads();
    bf16x8 af[4], bf_[4];
#pragma unroll
    for (int m = 0; m < 4; ++m) af[m] = *(const bf16x8*)&lds[abase + m * 512];
#pragma unroll
    for (int n = 0; n < 4; ++n) bf_[n] = *(const bf16x8*)&lds[T_BH + bbase + n * 512];
#pragma unroll
    for (int m = 0; m < 4; ++m)
#pragma unroll
      for (int n = 0; n < 4; ++n)
        acc[m][n] = mfma16(af[m], bf_[n], acc[m][n]);
    __syncthreads();
  }

#pragma unroll
  for (int m = 0; m < 4; ++m) {
#pragma unroll
    for (int n = 0; n < 4; ++n) {
      const int rg0 = m0 + wr + m * 16 + l4 * 4;
      const int cg  = n0 + wc + n * 16 + li;
      if constexpr (OUTMODE == 1) {
        u16* Cs = (u16*)C0;
#pragma unroll
        for (int r = 0; r < 4; ++r) Cs[(size_t)(rg0 + r) * N + cg] = f2bf(acc[m][n][r]);
      } else if constexpr (OUTMODE == 2) {
        u16* Vt = (u16*)C0;   // Vt[b][d][s]
        ushort4 pk;
        pk.x = f2bf(acc[m][n][0]); pk.y = f2bf(acc[m][n][1]);
        pk.z = f2bf(acc[m][n][2]); pk.w = f2bf(acc[m][n][3]);
        *(ushort4*)&Vt[(size_t)(rg0 >> 11) * 4194304 + (size_t)cg * 2048 + (rg0 & 2047)] = pk;
      } else {
        float* Cf = (float*)C0;
#pragma unroll
        for (int r = 0; r < 4; ++r) Cf[(size_t)(rg0 + r) * N + cg] = acc[m][n][r];
      }
    }
  }
}

// ================= two-pass causal attention, swizzled LDS-staged K =================
#define C2EXP 0.1275174381027786f   // SCALE * log2(e)

// ---- pass A (split-k): partial (m,l) per 512-wide k chunk ----
__global__ __launch_bounds__(256) void attn_lse_part(
    const u16* __restrict__ Qh, const u16* __restrict__ Ql,
    const u16* __restrict__ Kh, const u16* __restrict__ Kl,
    float* __restrict__ Mp, float* __restrict__ Lp) {
  const int j = blockIdx.x, qt = 15 - (int)blockIdx.y, hb = blockIdx.z;
  const int b = hb >> 4, h = hb & 15;
  const int tid = threadIdx.x;
  const int nch = (qt >> 2) + 1;
  if (j >= nch) {
    if (tid < 128) {
      const size_t o = ((size_t)hb * 4 + j) * 2048 + qt * 128 + tid;
      Mp[o] = -3.0e38f; Lp[o] = 0.f;
    }
    return;
  }
  __shared__ __align__(16) u16 kb[16384];
  const int wave = tid >> 6, lane = tid & 63;
  const int li = lane & 15, l4 = lane >> 4;
  const int q0w = qt * 128 + wave * 32;
  const int rs = ((li << 6) | (l4 << 4)) ^ (((li >> 1) & 7) << 4);

  bf16x8 qfh[2][4], qfl[2][4];
#pragma unroll
  for (int mf = 0; mf < 2; ++mf) {
    const size_t qo = ((size_t)(b * 2048 + q0w + mf * 16 + li)) * 2048 + h * 128 + l4 * 8;
#pragma unroll
    for (int ks = 0; ks < 4; ++ks) {
      qfh[mf][ks] = *(const bf16x8*)&Qh[qo + ks * 32];
      qfl[mf][ks] = *(const bf16x8*)&Ql[qo + ks * 32];
    }
  }
  float m[2][4], l[2][4];
#pragma unroll
  for (int mf = 0; mf < 2; ++mf)
#pragma unroll
    for (int r = 0; r < 4; ++r) { m[mf][r] = -3.0e38f; l[mf][r] = 0.f; }

  const int kst = j * 8;
  const int ken = min(j * 8 + 8, qt * 2 + 2);
  const size_t kgbase = ((size_t)b * 2048) * 2048 + h * 128;
  const f32x4 fz = {0.f, 0.f, 0.f, 0.f};

#pragma unroll 1
  for (int t = kst; t < ken; ++t) {
    __syncthreads();
#pragma unroll
    for (int i = 0; i < 4; ++i) {
      const int o = (tid + i * 256) * 16;
      const int op = o ^ (((o >> 7) & 7) << 4);
      const int dck = op >> 12, s = (op >> 6) & 63, dl = (op >> 1) & 31;
      const size_t g = kgbase + (size_t)(t * 64 + s) * 2048 + dck * 32 + dl;
      cp16(Kh + g, kb + (o >> 1));
      cp16(Kl + g, kb + 8192 + (o >> 1));
    }
    __syncthreads();
#pragma unroll
    for (int sn = 0; sn < 4; ++sn) {
      if (64 * t + 16 * sn <= q0w + 31) {
        f32x4 a0 = fz, a1 = fz;
        __builtin_amdgcn_s_setprio(1);
#pragma unroll
        for (int ks = 0; ks < 4; ++ks) {
          const bf16x8 kh = *(const bf16x8*)((const char*)kb + ks * 4096 + (sn << 10) + rs);
          const bf16x8 kl = *(const bf16x8*)((const char*)kb + 16384 + ks * 4096 + (sn << 10) + rs);
          a0 = mfma16(qfh[0][ks], kh, a0);
          a0 = mfma16(qfh[0][ks], kl, a0);
          a0 = mfma16(qfl[0][ks], kh, a0);
          a1 = mfma16(qfh[1][ks], kh, a1);
          a1 = mfma16(qfh[1][ks], kl, a1);
          a1 = mfma16(qfl[1][ks], kh, a1);
        }
        __builtin_amdgcn_s_setprio(0);
        const int kg = t * 64 + sn * 16 + li;
#pragma unroll
        for (int r = 0; r < 4; ++r) {
          {
            const float aa = (kg <= q0w + l4 * 4 + r) ? a0[r] : -3.3e38f;
            if (__all(aa <= m[0][r])) {
              l[0][r] += EXP2((aa - m[0][r]) * C2EXP);
            } else {
              const float mn = fmaxf(m[0][r], aa);
              l[0][r] = l[0][r] * EXP2((m[0][r] - mn) * C2EXP) + EXP2((aa - mn) * C2EXP);
              m[0][r] = mn;
            }
          }
          {
            const float aa = (kg <= q0w + 16 + l4 * 4 + r) ? a1[r] : -3.3e38f;
            if (__all(aa <= m[1][r])) {
              l[1][r] += EXP2((aa - m[1][r]) * C2EXP);
            } else {
              const float mn = fmaxf(m[1][r], aa);
              l[1][r] = l[1][r] * EXP2((m[1][r] - mn) * C2EXP) + EXP2((aa - mn) * C2EXP);
              m[1][r] = mn;
            }
          }
        }
      }
    }
  }
#pragma unroll
  for (int off = 1; off <= 8; off <<= 1) {
#pragma unroll
    for (int mf = 0; mf < 2; ++mf)
#pragma unroll
      for (int r = 0; r < 4; ++r) {
        const float om = __shfl_xor(m[mf][r], off, 64);
        const float ol = __shfl_xor(l[mf][r], off, 64);
        const float mn = fmaxf(m[mf][r], om);
        l[mf][r] = l[mf][r] * EXP2((m[mf][r] - mn) * C2EXP) + ol * EXP2((om - mn) * C2EXP);
        m[mf][r] = mn;
      }
  }
  if (li == 0) {
#pragma unroll
    for (int mf = 0; mf < 2; ++mf)
#pragma unroll
      for (int r = 0; r < 4; ++r) {
        const size_t o = ((size_t)hb * 4 + j) * 2048 + q0w + mf * 16 + l4 * 4 + r;
        Mp[o] = m[mf][r];
        Lp[o] = l[mf][r];
      }
  }
}

// ---- pass A merge ----
__global__ __launch_bounds__(256) void attn_lse_merge(
    const float* __restrict__ Mp, const float* __restrict__ Lp, float* __restrict__ LSE) {
  const int id = blockIdx.x * 256 + threadIdx.x;
  const int q = id & 2047, hb = id >> 11;
  const size_t base = (size_t)hb * 4 * 2048 + q;
  float m = Mp[base], l = Lp[base];
#pragma unroll
  for (int jj = 1; jj < 4; ++jj) {
    const float om = Mp[base + jj * 2048];
    const float ol = Lp[base + jj * 2048];
    const float mn = fmaxf(m, om);
    l = l * EXP2((m - mn) * C2EXP) + ol * EXP2((om - mn) * C2EXP);
    m = mn;
  }
  LSE[(size_t)hb * 2048 + q] = m * C2EXP + LOG2(l);
}

// ---- pass B: Psum (128q x 128k tiles, 64KB dyn LDS) ----
__global__ __launch_bounds__(256) void attn_psum(
    const u16* __restrict__ Qh, const u16* __restrict__ Ql,
    const u16* __restrict__ Kh, const u16* __restrict__ Kl,
    const float* __restrict__ LSE, u16* __restrict__ Psum) {
  const int kt = blockIdx.x, qt = blockIdx.y, b = blockIdx.z;
  const int q0 = qt * 128, k0 = kt * 128;
  const int tid = threadIdx.x;

  if (kt > qt) {
    const size_t o = ((size_t)(b * 2048 + q0 + (tid >> 1))) * 2048 + k0 + (tid & 1) * 64;
    const uint4 z = {0u, 0u, 0u, 0u};
#pragma unroll
    for (int j2 = 0; j2 < 8; ++j2) *(uint4*)&Psum[o + j2 * 8] = z;
    return;
  }

  extern __shared__ u16 kb2[];   // 65536 B
  const int wave = tid >> 6, lane = tid & 63;
  const int li = lane & 15, l4 = lane >> 4;
  const int q0w = q0 + wave * 32;
  const int rs = ((li << 6) | (l4 << 4)) ^ (((li >> 1) & 7) << 4);
  const int snmax = (kt == qt) ? (wave * 2 + 2) : 8;

  const f32x4 fz = {0.f, 0.f, 0.f, 0.f};
  f32x4 ps[2][8];
#pragma unroll
  for (int mf = 0; mf < 2; ++mf)
#pragma unroll
    for (int sn = 0; sn < 8; ++sn) ps[mf][sn] = fz;

  const size_t kgbase = ((size_t)(b * 2048 + k0)) * 2048;
  const size_t qbase0 = ((size_t)(b * 2048 + q0w + li)) * 2048 + l4 * 8;
  const size_t qbase1 = qbase0 + (size_t)16 * 2048;
  const size_t lbase  = (size_t)(b * 16) * 2048 + q0w + l4 * 4;

#pragma unroll 1
  for (int h = 0; h < 16; ++h) {
    __syncthreads();
#pragma unroll
    for (int i = 0; i < 8; ++i) {
      const int o = (tid + i * 256) * 16;
      const int op = o ^ (((o >> 7) & 7) << 4);
      const int dck = op >> 13, s = (op >> 6) & 127, dl = (op >> 1) & 31;
      const size_t g = kgbase + (size_t)s * 2048 + h * 128 + dck * 32 + dl;
      cp16(Kh + g, kb2 + (o >> 1));
      cp16(Kl + g, kb2 + 16384 + (o >> 1));
    }
    bf16x8 qfh0[4], qfl0[4], qfh1[4], qfl1[4];
    float clse[2][4];
#pragma unroll
    for (int ks = 0; ks < 4; ++ks) {
      qfh0[ks] = *(const bf16x8*)&Qh[qbase0 + (size_t)h * 128 + ks * 32];
      qfl0[ks] = *(const bf16x8*)&Ql[qbase0 + (size_t)h * 128 + ks * 32];
      qfh1[ks] = *(const bf16x8*)&Qh[qbase1 + (size_t)h * 128 + ks * 32];
      qfl1[ks] = *(const bf16x8*)&Ql[qbase1 + (size_t)h * 128 + ks * 32];
    }
#pragma unroll
    for (int mf = 0; mf < 2; ++mf)
#pragma unroll
      for (int r = 0; r < 4; ++r)
        clse[mf][r] = LSE[lbase + (size_t)h * 2048 + mf * 16 + r];
    __syncthreads();

#pragma unroll
    for (int sn = 0; sn < 8; ++sn) {
      if (sn < snmax) {
        f32x4 a0 = fz, a1 = fz;
        __builtin_amdgcn_s_setprio(1);
#pragma unroll
        for (int ks = 0; ks < 4; ++ks) {
          const bf16x8 kh = *(const bf16x8*)((const char*)kb2 + ks * 8192 + (sn << 10) + rs);
          const bf16x8 kl = *(const bf16x8*)((const char*)kb2 + 32768 + ks * 8192 + (sn << 10) + rs);
          a0 = mfma16(qfh0[ks], kh, a0);
          a0 = mfma16(qfh0[ks], kl, a0);
          a0 = mfma16(qfl0[ks], kh, a0);
          a1 = mfma16(qfh1[ks], kh, a1);
          a1 = mfma16(qfh1[ks], kl, a1);
          a1 = mfma16(qfl1[ks], kh, a1);
        }
        __builtin_amdgcn_s_setprio(0);
        const int kg = k0 + sn * 16 + li;
#pragma unroll
        for (int r = 0; r < 4; ++r) {
          if (kg <= q0w + l4 * 4 + r)      ps[0][sn][r] += EXP2(a0[r] * C2EXP - clse[0][r]);
          if (kg <= q0w + 16 + l4 * 4 + r) ps[1][sn][r] += EXP2(a1[r] * C2EXP - clse[1][r]);
        }
      }
    }
  }

#pragma unroll
  for (int mf = 0; mf < 2; ++mf)
#pragma unroll
    for (int sn = 0; sn < 8; ++sn) {
      const size_t o0 = ((size_t)(b * 2048 + q0w + mf * 16 + l4 * 4)) * 2048 + k0 + sn * 16 + li;
#pragma unroll
      for (int r = 0; r < 4; ++r) Psum[o0 + (size_t)r * 2048] = f2bf(ps[mf][sn][r]);
    }
}

// ---------------- launch ----------------
extern "C" void kernel_launch(void* const* d_in, const int* in_sizes, int n_in,
                              void* d_out, int out_size, void* d_ws, size_t ws_size,
                              hipStream_t stream) {
  (void)in_sizes; (void)n_in; (void)out_size; (void)ws_size;
  const float* x  = (const float*)d_in[0];
  const float* Wq = (const float*)d_in[1];
  const float* Wk = (const float*)d_in[2];
  const float* Wv = (const float*)d_in[3];
  const float* Wo = (const float*)d_in[4];
  u16* ws = (u16*)d_ws;
  const size_t E8 = 8388608, E4 = 4194304;
  u16* xh = ws;
  u16* xl = ws + E8;
  u16* Qh = ws + 2 * E8;
  u16* Ql = ws + 3 * E8;
  u16* Kh = ws + 4 * E8;
  u16* Kl = ws + 5 * E8;
  u16* Vt = ws + 6 * E8;            // [b][d][s]; holds WkT before the V GEMM overwrites it
  u16* WTh = ws + 7 * E8;           // WqT hi
  u16* WTl = ws + 7 * E8 + E4;      // WqT lo (LSE/partials after Q/K done)
  u16* WTb = ws + 7 * E8 + 2 * E4;  // WvT hi, later WoT hi
  u16* WkTh = Vt;                   // WkT parks in the Vt region (dead until V GEMM)
  u16* WkTl = Vt + E4;
  float* LSEf = (float*)WTl;        // 65536 f32
  float* Mp   = LSEf + 65536;       // 262144 f32
  float* Lp   = Mp + 262144;        // 262144 f32
  u16* Psum = xl;
  u16* out1 = xh;
  // total ws use: 7*E8 + 3*E4 = 136 MiB (R11-proven)

  split_pair<<<8192, 256, 0, stream>>>((const float4*)x, xh, xl);

  transpose_split<true ><<<dim3(32, 32), 256, 0, stream>>>(Wq, WTh, WTl);
  transpose_split<true ><<<dim3(32, 32), 256, 0, stream>>>(Wk, WkTh, WkTl);
  transpose_split<false><<<dim3(32, 32), 256, 0, stream>>>(Wv, WTb, nullptr);

  // fused Q+K projection with SHARED A staging + swizzled LDS: 512 blocks, 48KB LDS
  gemm_qk<<<dim3(16, 32), 256, 49152, stream>>>(
      xh, xl, WTh, WTl, WkTh, WkTl, Qh, Ql, Kh, Kl);

  gemm_bt<2, false><<<dim3(16, 32), 256, 16384, stream>>>(
      xh, WTb, Vt, 4096, 2048, 2048, 0);

  attn_lse_part<<<dim3(4, 16, 32), 256, 0, stream>>>(Qh, Ql, Kh, Kl, Mp, Lp);
  attn_lse_merge<<<256, 256, 0, stream>>>(Mp, Lp, LSEf);
  attn_psum<<<dim3(16, 16, 2), 256, 65536, stream>>>(Qh, Ql, Kh, Kl, LSEf, Psum);

  gemm_bt<1, true><<<dim3(16, 32), 256, 16384, stream>>>(
      Psum, Vt, out1, 4096, 2048, 2048, 4194304);

  transpose_split<false><<<dim3(32, 32), 256, 0, stream>>>(Wo, WTb, nullptr);
  gemm_bt<3, false><<<dim3(16, 32), 256, 16384, stream>>>(
      out1, WTb, d_out, 4096, 2048, 2048, 0);
}